// Round 27
// baseline (41.880 us; speedup 1.0000x reference)
//
#include <hip/hip_runtime.h>
#include <math.h>

// Problem constants: B=1, S=256, HID=1024, H=16, KV=8, D=64, N_REP=2
#define SCALE 0.125f   // 1/sqrt(64)
#define LOG2E 1.44269504088896340736f

typedef short short8 __attribute__((ext_vector_type(8)));
typedef float floatx4 __attribute__((ext_vector_type(4)));

static __device__ __forceinline__ ushort f2bf(float x) {
  uint32_t b = __float_as_uint(x);
  uint32_t r = (b + 0x7FFFu + ((b >> 16) & 1u)) >> 16;   // RNE
  return (ushort)r;
}
static __device__ __forceinline__ float bf2f(ushort u) {
  return __uint_as_float(((uint32_t)u) << 16);
}

// ---------------------------------------------------------------------------
// MFMA bf16 GEMM 1: X(256x1024) @ [Wq|Wk|Wv](1024x2048) -> QKV partials.
// K-split 4. grid = 512 (4 ksplit * 128 tiles), block = 256. (verified R8/R13)
// ---------------------------------------------------------------------------
__global__ __launch_bounds__(256) void gemm_qkv_kernel(
    const float* __restrict__ X, const float* __restrict__ Wq,
    const float* __restrict__ Wk, const float* __restrict__ Wv,
    float* __restrict__ Cp) {
  __shared__ ushort As[4096];
  __shared__ ushort Bs[4096];
  char* Asc = (char*)As;
  char* Bsc = (char*)Bs;
  const int bx = blockIdx.x;
  const int ks = bx >> 7;            // 0..3
  const int tile = bx & 127;         // 4 m-tiles x 32 n-tiles
  const int tile_n = tile & 31, tile_m = tile >> 5;
  const int n0 = tile_n * 64, m0 = tile_m * 64;
  const float* Bp; int ldb, bc0;
  if (n0 < 1024)      { Bp = Wq; ldb = 1024; bc0 = n0; }
  else if (n0 < 1536) { Bp = Wk; ldb = 512;  bc0 = n0 - 1024; }
  else                { Bp = Wv; ldb = 512;  bc0 = n0 - 1536; }
  const int t = threadIdx.x;
  const int arow = t >> 4, acg = t & 15;
  const int bng = t & 15;
  const int kbeg = ks * 256;
  float4 ra[4], rb0[2], rb1[2];
  auto LOAD = [&](int k0) {
    #pragma unroll
    for (int i = 0; i < 4; ++i)
      ra[i] = *reinterpret_cast<const float4*>(X + (size_t)(m0 + arow + 16 * i) * 1024 + k0 + acg * 4);
    #pragma unroll
    for (int i = 0; i < 2; ++i) {
      int k = 2 * ((t >> 4) + 16 * i);
      rb0[i] = *reinterpret_cast<const float4*>(Bp + (size_t)(k0 + k) * ldb + bc0 + bng * 4);
      rb1[i] = *reinterpret_cast<const float4*>(Bp + (size_t)(k0 + k + 1) * ldb + bc0 + bng * 4);
    }
  };
  LOAD(kbeg);
  const int wid = t >> 6, wr = wid >> 1, wc = wid & 1, lane = t & 63;
  const int lr = lane & 15, lk = lane >> 4;
  const int sw = (lr & 7) << 4;
  floatx4 acc[2][2];
  #pragma unroll
  for (int mt = 0; mt < 2; ++mt)
    #pragma unroll
    for (int nt = 0; nt < 2; ++nt)
      acc[mt][nt] = (floatx4){0.f, 0.f, 0.f, 0.f};
  for (int kt = 0; kt < 4; ++kt) {
    #pragma unroll
    for (int i = 0; i < 4; ++i) {
      int row = arow + 16 * i;
      ushort4 w;
      w.x = f2bf(ra[i].x); w.y = f2bf(ra[i].y); w.z = f2bf(ra[i].z); w.w = f2bf(ra[i].w);
      *reinterpret_cast<ushort4*>(Asc + row * 128 + ((acg * 8) ^ ((row & 7) << 4))) = w;
    }
    #pragma unroll
    for (int i = 0; i < 2; ++i) {
      int k = 2 * ((t >> 4) + 16 * i);
      const float* p0 = (const float*)&rb0[i];
      const float* p1 = (const float*)&rb1[i];
      #pragma unroll
      for (int j = 0; j < 4; ++j) {
        int n = bng * 4 + j;
        uint32_t v = (uint32_t)f2bf(p0[j]) | ((uint32_t)f2bf(p1[j]) << 16);
        *reinterpret_cast<uint32_t*>(Bsc + n * 128 + ((k * 2) ^ ((n & 7) << 4))) = v;
      }
    }
    __syncthreads();
    if (kt + 1 < 4) LOAD(kbeg + 64 * (kt + 1));
    #pragma unroll
    for (int kc = 0; kc < 2; ++kc) {
      short8 af[2], bf[2];
      #pragma unroll
      for (int mt = 0; mt < 2; ++mt)
        af[mt] = *reinterpret_cast<const short8*>(
            Asc + (wr * 32 + mt * 16 + lr) * 128 + ((kc * 64 + lk * 16) ^ sw));
      #pragma unroll
      for (int nt = 0; nt < 2; ++nt)
        bf[nt] = *reinterpret_cast<const short8*>(
            Bsc + (wc * 32 + nt * 16 + lr) * 128 + ((kc * 64 + lk * 16) ^ sw));
      #pragma unroll
      for (int mt = 0; mt < 2; ++mt)
        #pragma unroll
        for (int nt = 0; nt < 2; ++nt)
          acc[mt][nt] = __builtin_amdgcn_mfma_f32_16x16x32_bf16(af[mt], bf[nt], acc[mt][nt], 0, 0, 0);
    }
    __syncthreads();
  }
  float* Co = Cp + (size_t)ks * 524288;
  #pragma unroll
  for (int mt = 0; mt < 2; ++mt)
    #pragma unroll
    for (int nt = 0; nt < 2; ++nt)
      #pragma unroll
      for (int r = 0; r < 4; ++r) {
        int row = wr * 32 + mt * 16 + lk * 4 + r;
        int col = wc * 32 + nt * 16 + lr;
        Co[(size_t)(m0 + row) * 2048 + n0 + col] = acc[mt][nt][r];
      }
}

// ---------------------------------------------------------------------------
// Reduce the 4 QKV partials + RoPE on q/k heads. grid = 1280, block = 256.
// ---------------------------------------------------------------------------
__global__ __launch_bounds__(256) void rope_reduce_kernel(
    const float* __restrict__ Cp, float* __restrict__ QKV,
    const float* __restrict__ cs, const float* __restrict__ sn) {
  int idx = blockIdx.x * 256 + threadIdx.x;
  const float* P0 = Cp;
  const float* P1 = Cp + 524288;
  const float* P2p = Cp + 1048576;
  const float* P3 = Cp + 1572864;
  if (idx < 196608) {                 // 256 s * 24 heads * 32 pairs
    int dp = idx & 31;
    int head = (idx >> 5) % 24;       // 0..15 q heads, 16..23 k heads
    int s = idx / 768;
    int base = s * 2048 + head * 64;
    int a1 = base + dp, a2 = base + dp + 32;
    float x1 = P0[a1] + P1[a1] + P2p[a1] + P3[a1];
    float x2 = P0[a2] + P1[a2] + P2p[a2] + P3[a2];
    float c1 = cs[s * 64 + dp],      s1v = sn[s * 64 + dp];
    float c2 = cs[s * 64 + dp + 32], s2v = sn[s * 64 + dp + 32];
    QKV[a1] = x1 * c1 - x2 * s1v;   // q' = q*cos + rot_half(q)*sin
    QKV[a2] = x2 * c2 + x1 * s2v;
  } else {
    int i2 = idx - 196608;            // 131072 v elements
    int s = i2 >> 9, c = 1536 + (i2 & 511);
    int a = s * 2048 + c;
    QKV[a] = P0[a] + P1[a] + P2p[a] + P3[a];
  }
}

// ---------------------------------------------------------------------------
// FUSED QK^T + softmax + p_diff + PV, v10 = R24 (best) + LDS-TRAFFIC DIET:
// aw|p packed bf16 in one u32 row (awp) -> ONE b128 broadcast per 4 iters
// (was two: aw fp32 + p fp32). LDS pipe is shared by all 16 waves/CU
// (~11 cyc/iter -> ~8); +2 cheap unpack VALU/iter. aw bf16 (R13-verified),
// p bf16 in S3 (R14-verified). LDS 131KB, grid 256, block 1024.
// ---------------------------------------------------------------------------
__global__ __launch_bounds__(1024) void pdiff_fused_kernel(
    const float* __restrict__ QKV, float* __restrict__ pOut,
    float* __restrict__ qkpart, float* __restrict__ attn_out) {
  __shared__ ushort ksh[16384];       // 32KB swizzled [t][d] bf16 (MFMA B)
  __shared__ uint32_t kvT[64 * 258];  // 64.5KB transposed [d][t]: k lo | v hi
  __shared__ ushort qsh[1024];        // 2KB  swizzled [a][d] bf16 (16 rows)
  __shared__ float awsh[16][260];     // 16.25KB fp32 (scale^2*log2e*qk, masked)
  __shared__ uint32_t awp[16][260];   // 16.25KB: aw bf16 lo | p bf16 hi
  char* kshc = (char*)ksh;
  char* qshc = (char*)qsh;
  const int g = blockIdx.x >> 5;
  const int u = blockIdx.x & 31;
  const int t = threadIdx.x;
  // stage k (swizzled, for MFMA) + kvT (transposed packed, for t-loop)
  #pragma unroll
  for (int i = 0; i < 4; ++i) {
    int fi = t + i * 1024;             // 4096 float4 slots
    int tt = fi >> 4, c = (fi & 15) * 4;
    float4 kv = *reinterpret_cast<const float4*>(QKV + (size_t)tt * 2048 + 1024 + g * 64 + c);
    float4 vv = *reinterpret_cast<const float4*>(QKV + (size_t)tt * 2048 + 1536 + g * 64 + c);
    ushort4 wk;
    wk.x = f2bf(kv.x); wk.y = f2bf(kv.y); wk.z = f2bf(kv.z); wk.w = f2bf(kv.w);
    *reinterpret_cast<ushort4*>(kshc + tt * 128 + ((c * 2) ^ ((tt & 7) << 4))) = wk;
    kvT[(c + 0) * 258 + tt] = (uint32_t)wk.x | ((uint32_t)f2bf(vv.x) << 16);
    kvT[(c + 1) * 258 + tt] = (uint32_t)wk.y | ((uint32_t)f2bf(vv.y) << 16);
    kvT[(c + 2) * 258 + tt] = (uint32_t)wk.z | ((uint32_t)f2bf(vv.z) << 16);
    kvT[(c + 3) * 258 + tt] = (uint32_t)wk.w | ((uint32_t)f2bf(vv.w) << 16);
  }
  if (t < 512) { // stage the 16 q rows: a = pr*8 + mr*4 + jo
    int a = t >> 5;                    // 0..15
    int c = (t & 31) * 2;              // 0..62
    int pr = a >> 3, mr = (a >> 2) & 1, jo = a & 3;
    int s = mr ? 255 - (4 * u + jo) : 4 * u + jo;
    int hh = 2 * g + pr;
    float2 qv = *reinterpret_cast<const float2*>(QKV + (size_t)s * 2048 + hh * 64 + c);
    uint32_t pk = (uint32_t)f2bf(qv.x) | ((uint32_t)f2bf(qv.y) << 16);
    *reinterpret_cast<uint32_t*>(qshc + a * 128 + ((c * 2) ^ ((a & 7) << 4))) = pk;
  }
  __syncthreads();
  const int w = t >> 6, lane = t & 63;
  const int lr = lane & 15, lk = lane >> 4;
  const int sw = (lr & 7) << 4;
  const float AWS = SCALE * SCALE * LOG2E;
  // QK^T: 16 col-tiles, ONE per wave; awsh fp32 with causal mask baked in
  {
    int nt = w;
    floatx4 acc = (floatx4){0.f, 0.f, 0.f, 0.f};
    #pragma unroll
    for (int kc = 0; kc < 2; ++kc) {
      short8 af = *reinterpret_cast<const short8*>(
          qshc + lr * 128 + ((kc * 64 + lk * 16) ^ sw));
      int tt = nt * 16 + lr;
      short8 bf = *reinterpret_cast<const short8*>(
          kshc + tt * 128 + ((kc * 64 + lk * 16) ^ ((tt & 7) << 4)));
      acc = __builtin_amdgcn_mfma_f32_16x16x32_bf16(af, bf, acc, 0, 0, 0);
    }
    #pragma unroll
    for (int r = 0; r < 4; ++r) {
      int a = lk * 4 + r;
      int pr = a >> 3, mr = (a >> 2) & 1, jo = a & 3;
      int sa = mr ? 255 - (4 * u + jo) : 4 * u + jo;
      int tc = nt * 16 + lr;
      awsh[a][tc] = (tc <= sa) ? acc[r] * AWS : -1000.0f;
    }
  }
  __syncthreads();
  // wave w owns row a = w
  const int a = w;
  const int pr = a >> 3, mr = (a >> 2) & 1, jo = a & 3;
  const int h = 2 * g + pr;
  const int s = mr ? 255 - (4 * u + jo) : 4 * u + jo;
  size_t rowbase = ((size_t)h * 256 + s) * 256;
  // pre-loop: ep = 2^(8*aw); Sp shuffle-reduce; write packed aw|p row
  float awv[4], epv[4], sp = 0.f;
  #pragma unroll
  for (int i = 0; i < 4; ++i) {
    awv[i] = awsh[a][lane + i * 64];
    epv[i] = __builtin_amdgcn_exp2f(8.0f * awv[i]);
    sp += epv[i];
  }
  #pragma unroll
  for (int off = 32; off; off >>= 1) sp += __shfl_xor(sp, off);
  float invSp = 1.f / sp;
  float p2 = 0.f;
  #pragma unroll
  for (int i = 0; i < 4; ++i) {
    int tc = lane + i * 64;
    float pv = epv[i] * invSp;
    awp[a][tc] = (uint32_t)f2bf(awv[i]) | ((uint32_t)f2bf(pv) << 16);
    pOut[rowbase + tc] = pv;                 // masked -> ep=0 -> p=0
    p2 = fmaf(pv, pv, p2);
  }
  #pragma unroll
  for (int off = 32; off; off >>= 1) p2 += __shfl_xor(p2, off);
  // slim t-loop: 1 b128 broadcast (aw|p) + 2 b64 (kv) per 4 iters
  float cd2 = (SCALE * LOG2E) * QKV[(size_t)s * 2048 + h * 64 + lane];
  float S1 = 0.f, S2 = 0.f, S3 = 0.f, AV = 0.f;
  const uint32_t* kvrow = &kvT[lane * 258];
  const uint32_t* aprow = awp[a];
  const int nt4 = (s + 4) & ~3;        // masked region contributes exact 0
  #pragma unroll 2
  for (int tb = 0; tb < nt4; tb += 4) {
    uint2 kvA = *reinterpret_cast<const uint2*>(&kvrow[tb]);
    uint2 kvB = *reinterpret_cast<const uint2*>(&kvrow[tb + 2]);
    uint4 ap4 = *reinterpret_cast<const uint4*>(&aprow[tb]);
    uint32_t kvj[4] = {kvA.x, kvA.y, kvB.x, kvB.y};
    uint32_t apj[4] = {ap4.x, ap4.y, ap4.z, ap4.w};
    #pragma unroll
    for (int j = 0; j < 4; ++j) {
      float kf = __uint_as_float(kvj[j] << 16);
      float vf = __uint_as_float(kvj[j] & 0xFFFF0000u);
      float aw = __uint_as_float(apj[j] << 16);
      float pv = __uint_as_float(apj[j] & 0xFFFF0000u);
      float e = __builtin_amdgcn_exp2f(fmaf(-cd2, kf, aw));
      S1 += e;
      S2 = fmaf(e, e, S2);
      S3 = fmaf(e, pv, S3);
      AV = fmaf(pv, vf, AV);
    }
  }
  float invS1 = 1.f / S1;
  float qk = S2 * invS1 * invS1 - 2.f * S3 * invS1 + p2;
  attn_out[(size_t)s * 1024 + h * 64 + lane] = AV;
  qkpart[((size_t)h * 256 + s) * 64 + lane] = qk;
}

// ---------------------------------------------------------------------------
// GEMM 2 + tail in ONE dispatch. Blocks 0..255: 32x32-tile FULL-K bf16 MFMA,
// direct write to out. Blocks 256..263: qk (sum 256 rows) / v/o importance
// (sum |attn_out|). grid = 264, block = 256.  (verified R22/R23)
// ---------------------------------------------------------------------------
__global__ __launch_bounds__(256) void gemm_o_tail_kernel(
    const float* __restrict__ A, const float* __restrict__ W,
    const float* __restrict__ qkpart, float* __restrict__ out,
    float* __restrict__ qkout, float* __restrict__ vout,
    float* __restrict__ oout) {
  __shared__ ushort As[2048];   // 32 rows x 64 k bf16, XOR swizzle
  __shared__ ushort Bs[2048];   // 32 n    x 64 k
  char* Asc = (char*)As;
  char* Bsc = (char*)Bs;
  const int b = blockIdx.x, t = threadIdx.x;
  if (b < 256) {
    const int tm = b >> 5, tn = b & 31;       // 8 m x 32 n tiles
    const int m0 = tm * 32, n0 = tn * 32;
    const int arow = t >> 3, aslot = t & 7;   // A: 32 rows x 16 slots
    const int kp = t >> 3, ng = t & 7;        // B: 32 kpairs x 8 ngroups
    float4 ra[2], rb0, rb1;
    auto LOAD = [&](int k0) {
      #pragma unroll
      for (int i = 0; i < 2; ++i)
        ra[i] = *reinterpret_cast<const float4*>(A + (size_t)(m0 + arow) * 1024 + k0 + (aslot + 8 * i) * 4);
      rb0 = *reinterpret_cast<const float4*>(W + (size_t)(k0 + 2 * kp) * 1024 + n0 + ng * 4);
      rb1 = *reinterpret_cast<const float4*>(W + (size_t)(k0 + 2 * kp + 1) * 1024 + n0 + ng * 4);
    };
    LOAD(0);
    const int wid = t >> 6, qm = wid >> 1, qn = wid & 1, lane = t & 63;
    const int lr = lane & 15, lk = lane >> 4;
    const int sw = (lr & 7) << 4;
    floatx4 acc = (floatx4){0.f, 0.f, 0.f, 0.f};
    for (int kt = 0; kt < 16; ++kt) {
      #pragma unroll
      for (int i = 0; i < 2; ++i) {
        int c = (aslot + 8 * i) * 4;
        ushort4 wv;
        wv.x = f2bf(ra[i].x); wv.y = f2bf(ra[i].y); wv.z = f2bf(ra[i].z); wv.w = f2bf(ra[i].w);
        *reinterpret_cast<ushort4*>(Asc + arow * 128 + ((c * 2) ^ ((arow & 7) << 4))) = wv;
      }
      {
        const float* p0 = (const float*)&rb0;
        const float* p1 = (const float*)&rb1;
        #pragma unroll
        for (int j = 0; j < 4; ++j) {
          int n = ng * 4 + j;
          uint32_t v = (uint32_t)f2bf(p0[j]) | ((uint32_t)f2bf(p1[j]) << 16);
          *reinterpret_cast<uint32_t*>(Bsc + n * 128 + ((kp * 4) ^ ((n & 7) << 4))) = v;
        }
      }
      __syncthreads();
      if (kt + 1 < 16) LOAD(64 * (kt + 1));
      #pragma unroll
      for (int kc = 0; kc < 2; ++kc) {
        short8 af = *reinterpret_cast<const short8*>(
            Asc + (qm * 16 + lr) * 128 + ((kc * 64 + lk * 16) ^ sw));
        short8 bf = *reinterpret_cast<const short8*>(
            Bsc + (qn * 16 + lr) * 128 + ((kc * 64 + lk * 16) ^ sw));
        acc = __builtin_amdgcn_mfma_f32_16x16x32_bf16(af, bf, acc, 0, 0, 0);
      }
      __syncthreads();
    }
    #pragma unroll
    for (int r = 0; r < 4; ++r) {
      int row = m0 + qm * 16 + lk * 4 + r;
      int col = n0 + qn * 16 + lr;
      out[(size_t)row * 1024 + col] = acc[r];
    }
  } else {
    int idx = (b - 256) * 256 + t;            // 0..2047
    if (idx < 1024) {
      int h = idx >> 6, d = idx & 63;
      float sum = 0.f;
      for (int j = 0; j < 256; ++j) sum += qkpart[((size_t)h * 256 + j) * 64 + d];
      qkout[idx] = sum;
    } else {
      int c = idx - 1024;
      float sum = 0.f;
      for (int s = 0; s < 256; ++s) sum += fabsf(A[(size_t)s * 1024 + c]);
      vout[c] = sum;
      oout[c] = sum;
    }
  }
}

// ---------------------------------------------------------------------------
extern "C" void kernel_launch(void* const* d_in, const int* in_sizes, int n_in,
                              void* d_out, int out_size, void* d_ws, size_t ws_size,
                              hipStream_t stream) {
  const float* X    = (const float*)d_in[0];   // hidden_states (1,256,1024)
  const float* cosp = (const float*)d_in[1];   // (1,256,64)
  const float* sinp = (const float*)d_in[2];   // (1,256,64)
  // d_in[3] attention_mask: causal, implemented analytically
  const float* Wq   = (const float*)d_in[4];   // (1024,1024)
  const float* Wk   = (const float*)d_in[5];   // (1024,512)
  const float* Wv   = (const float*)d_in[6];   // (1024,512)
  const float* Wo   = (const float*)d_in[7];   // (1024,1024)

  float* out  = (float*)d_out;                 // 262144
  float* pOut = out + 262144;                  // 1048576
  float* qki  = pOut + 1048576;                // 1024
  float* vi   = qki + 1024;                    // 1024
  float* oi   = vi + 1024;                     // 1024

  float* ws       = (float*)d_ws;
  float* QKV      = ws;                        // 524288 (s-major, 2048 cols: q|k|v)
  float* attn_out = ws + 524288;               // 262144
  float* qkpart   = ws + 786432;               // 262144 (per-row qk)
  float* scratch  = ws + 1048576;              // 2097152 (QKV partials x4)

  hipLaunchKernelGGL(gemm_qkv_kernel, dim3(512), dim3(256), 0, stream, X, Wq, Wk, Wv, scratch);
  hipLaunchKernelGGL(rope_reduce_kernel, dim3(1280), dim3(256), 0, stream, scratch, QKV, cosp, sinp);
  hipLaunchKernelGGL(pdiff_fused_kernel, dim3(256), dim3(1024), 0, stream, QKV, pOut, qkpart, attn_out);
  hipLaunchKernelGGL(gemm_o_tail_kernel, dim3(264), dim3(256), 0, stream, attn_out, Wo, qkpart, out, qki, vi, oi);
}

// Round 28
// 41.096 us; speedup vs baseline: 1.0191x; 1.0191x over previous
//
#include <hip/hip_runtime.h>
#include <math.h>

// Problem constants: B=1, S=256, HID=1024, H=16, KV=8, D=64, N_REP=2
#define SCALE 0.125f   // 1/sqrt(64)
#define LOG2E 1.44269504088896340736f

typedef short short8 __attribute__((ext_vector_type(8)));
typedef float floatx4 __attribute__((ext_vector_type(4)));

static __device__ __forceinline__ ushort f2bf(float x) {
  uint32_t b = __float_as_uint(x);
  uint32_t r = (b + 0x7FFFu + ((b >> 16) & 1u)) >> 16;   // RNE
  return (ushort)r;
}
static __device__ __forceinline__ float bf2f(ushort u) {
  return __uint_as_float(((uint32_t)u) << 16);
}

// ---------------------------------------------------------------------------
// MFMA bf16 GEMM 1: X(256x1024) @ [Wq|Wk|Wv](1024x2048) -> QKV partials.
// K-split 4. grid = 512 (4 ksplit * 128 tiles), block = 256. (verified R8/R13)
// ---------------------------------------------------------------------------
__global__ __launch_bounds__(256) void gemm_qkv_kernel(
    const float* __restrict__ X, const float* __restrict__ Wq,
    const float* __restrict__ Wk, const float* __restrict__ Wv,
    float* __restrict__ Cp) {
  __shared__ ushort As[4096];
  __shared__ ushort Bs[4096];
  char* Asc = (char*)As;
  char* Bsc = (char*)Bs;
  const int bx = blockIdx.x;
  const int ks = bx >> 7;            // 0..3
  const int tile = bx & 127;         // 4 m-tiles x 32 n-tiles
  const int tile_n = tile & 31, tile_m = tile >> 5;
  const int n0 = tile_n * 64, m0 = tile_m * 64;
  const float* Bp; int ldb, bc0;
  if (n0 < 1024)      { Bp = Wq; ldb = 1024; bc0 = n0; }
  else if (n0 < 1536) { Bp = Wk; ldb = 512;  bc0 = n0 - 1024; }
  else                { Bp = Wv; ldb = 512;  bc0 = n0 - 1536; }
  const int t = threadIdx.x;
  const int arow = t >> 4, acg = t & 15;
  const int bng = t & 15;
  const int kbeg = ks * 256;
  float4 ra[4], rb0[2], rb1[2];
  auto LOAD = [&](int k0) {
    #pragma unroll
    for (int i = 0; i < 4; ++i)
      ra[i] = *reinterpret_cast<const float4*>(X + (size_t)(m0 + arow + 16 * i) * 1024 + k0 + acg * 4);
    #pragma unroll
    for (int i = 0; i < 2; ++i) {
      int k = 2 * ((t >> 4) + 16 * i);
      rb0[i] = *reinterpret_cast<const float4*>(Bp + (size_t)(k0 + k) * ldb + bc0 + bng * 4);
      rb1[i] = *reinterpret_cast<const float4*>(Bp + (size_t)(k0 + k + 1) * ldb + bc0 + bng * 4);
    }
  };
  LOAD(kbeg);
  const int wid = t >> 6, wr = wid >> 1, wc = wid & 1, lane = t & 63;
  const int lr = lane & 15, lk = lane >> 4;
  const int sw = (lr & 7) << 4;
  floatx4 acc[2][2];
  #pragma unroll
  for (int mt = 0; mt < 2; ++mt)
    #pragma unroll
    for (int nt = 0; nt < 2; ++nt)
      acc[mt][nt] = (floatx4){0.f, 0.f, 0.f, 0.f};
  for (int kt = 0; kt < 4; ++kt) {
    #pragma unroll
    for (int i = 0; i < 4; ++i) {
      int row = arow + 16 * i;
      ushort4 w;
      w.x = f2bf(ra[i].x); w.y = f2bf(ra[i].y); w.z = f2bf(ra[i].z); w.w = f2bf(ra[i].w);
      *reinterpret_cast<ushort4*>(Asc + row * 128 + ((acg * 8) ^ ((row & 7) << 4))) = w;
    }
    #pragma unroll
    for (int i = 0; i < 2; ++i) {
      int k = 2 * ((t >> 4) + 16 * i);
      const float* p0 = (const float*)&rb0[i];
      const float* p1 = (const float*)&rb1[i];
      #pragma unroll
      for (int j = 0; j < 4; ++j) {
        int n = bng * 4 + j;
        uint32_t v = (uint32_t)f2bf(p0[j]) | ((uint32_t)f2bf(p1[j]) << 16);
        *reinterpret_cast<uint32_t*>(Bsc + n * 128 + ((k * 2) ^ ((n & 7) << 4))) = v;
      }
    }
    __syncthreads();
    if (kt + 1 < 4) LOAD(kbeg + 64 * (kt + 1));
    #pragma unroll
    for (int kc = 0; kc < 2; ++kc) {
      short8 af[2], bf[2];
      #pragma unroll
      for (int mt = 0; mt < 2; ++mt)
        af[mt] = *reinterpret_cast<const short8*>(
            Asc + (wr * 32 + mt * 16 + lr) * 128 + ((kc * 64 + lk * 16) ^ sw));
      #pragma unroll
      for (int nt = 0; nt < 2; ++nt)
        bf[nt] = *reinterpret_cast<const short8*>(
            Bsc + (wc * 32 + nt * 16 + lr) * 128 + ((kc * 64 + lk * 16) ^ sw));
      #pragma unroll
      for (int mt = 0; mt < 2; ++mt)
        #pragma unroll
        for (int nt = 0; nt < 2; ++nt)
          acc[mt][nt] = __builtin_amdgcn_mfma_f32_16x16x32_bf16(af[mt], bf[nt], acc[mt][nt], 0, 0, 0);
    }
    __syncthreads();
  }
  float* Co = Cp + (size_t)ks * 524288;
  #pragma unroll
  for (int mt = 0; mt < 2; ++mt)
    #pragma unroll
    for (int nt = 0; nt < 2; ++nt)
      #pragma unroll
      for (int r = 0; r < 4; ++r) {
        int row = wr * 32 + mt * 16 + lk * 4 + r;
        int col = wc * 32 + nt * 16 + lr;
        Co[(size_t)(m0 + row) * 2048 + n0 + col] = acc[mt][nt][r];
      }
}

// ---------------------------------------------------------------------------
// Reduce the 4 QKV partials + RoPE on q/k heads. grid = 1280, block = 256.
// ---------------------------------------------------------------------------
__global__ __launch_bounds__(256) void rope_reduce_kernel(
    const float* __restrict__ Cp, float* __restrict__ QKV,
    const float* __restrict__ cs, const float* __restrict__ sn) {
  int idx = blockIdx.x * 256 + threadIdx.x;
  const float* P0 = Cp;
  const float* P1 = Cp + 524288;
  const float* P2p = Cp + 1048576;
  const float* P3 = Cp + 1572864;
  if (idx < 196608) {                 // 256 s * 24 heads * 32 pairs
    int dp = idx & 31;
    int head = (idx >> 5) % 24;       // 0..15 q heads, 16..23 k heads
    int s = idx / 768;
    int base = s * 2048 + head * 64;
    int a1 = base + dp, a2 = base + dp + 32;
    float x1 = P0[a1] + P1[a1] + P2p[a1] + P3[a1];
    float x2 = P0[a2] + P1[a2] + P2p[a2] + P3[a2];
    float c1 = cs[s * 64 + dp],      s1v = sn[s * 64 + dp];
    float c2 = cs[s * 64 + dp + 32], s2v = sn[s * 64 + dp + 32];
    QKV[a1] = x1 * c1 - x2 * s1v;   // q' = q*cos + rot_half(q)*sin
    QKV[a2] = x2 * c2 + x1 * s2v;
  } else {
    int i2 = idx - 196608;            // 131072 v elements
    int s = i2 >> 9, c = 1536 + (i2 & 511);
    int a = s * 2048 + c;
    QKV[a] = P0[a] + P1[a] + P2p[a] + P3[a];
  }
}

// ---------------------------------------------------------------------------
// FUSED QK^T + softmax + p_diff + PV, v7 (BEST, R24: 40.93us).
// Sp/P2 hoisted (lane-invariant, shuffle reduce); epsh holds NORMALIZED p
// fp32; awsh fp32; loop: 2x b64 kv + 2x b128 broadcast per 4 iters, 1 native
// v_exp + 4 fma chains (S1,S2,S3,AV). LDS 131KB, grid 256, block 1024.
// ---------------------------------------------------------------------------
__global__ __launch_bounds__(1024) void pdiff_fused_kernel(
    const float* __restrict__ QKV, float* __restrict__ pOut,
    float* __restrict__ qkpart, float* __restrict__ attn_out) {
  __shared__ ushort ksh[16384];       // 32KB swizzled [t][d] bf16 (MFMA B)
  __shared__ uint32_t kvT[64 * 258];  // 64.5KB transposed [d][t]: k lo | v hi
  __shared__ ushort qsh[1024];        // 2KB  swizzled [a][d] bf16 (16 rows)
  __shared__ float awsh[16][260];     // 16.25KB fp32 (scale^2*log2e*qk, masked)
  __shared__ float epsh[16][260];     // 16.25KB fp32 normalized p per row
  char* kshc = (char*)ksh;
  char* qshc = (char*)qsh;
  const int g = blockIdx.x >> 5;
  const int u = blockIdx.x & 31;
  const int t = threadIdx.x;
  // stage k (swizzled, for MFMA) + kvT (transposed packed, for t-loop)
  #pragma unroll
  for (int i = 0; i < 4; ++i) {
    int fi = t + i * 1024;             // 4096 float4 slots
    int tt = fi >> 4, c = (fi & 15) * 4;
    float4 kv = *reinterpret_cast<const float4*>(QKV + (size_t)tt * 2048 + 1024 + g * 64 + c);
    float4 vv = *reinterpret_cast<const float4*>(QKV + (size_t)tt * 2048 + 1536 + g * 64 + c);
    ushort4 wk;
    wk.x = f2bf(kv.x); wk.y = f2bf(kv.y); wk.z = f2bf(kv.z); wk.w = f2bf(kv.w);
    *reinterpret_cast<ushort4*>(kshc + tt * 128 + ((c * 2) ^ ((tt & 7) << 4))) = wk;
    kvT[(c + 0) * 258 + tt] = (uint32_t)wk.x | ((uint32_t)f2bf(vv.x) << 16);
    kvT[(c + 1) * 258 + tt] = (uint32_t)wk.y | ((uint32_t)f2bf(vv.y) << 16);
    kvT[(c + 2) * 258 + tt] = (uint32_t)wk.z | ((uint32_t)f2bf(vv.z) << 16);
    kvT[(c + 3) * 258 + tt] = (uint32_t)wk.w | ((uint32_t)f2bf(vv.w) << 16);
  }
  if (t < 512) { // stage the 16 q rows: a = pr*8 + mr*4 + jo
    int a = t >> 5;                    // 0..15
    int c = (t & 31) * 2;              // 0..62
    int pr = a >> 3, mr = (a >> 2) & 1, jo = a & 3;
    int s = mr ? 255 - (4 * u + jo) : 4 * u + jo;
    int hh = 2 * g + pr;
    float2 qv = *reinterpret_cast<const float2*>(QKV + (size_t)s * 2048 + hh * 64 + c);
    uint32_t pk = (uint32_t)f2bf(qv.x) | ((uint32_t)f2bf(qv.y) << 16);
    *reinterpret_cast<uint32_t*>(qshc + a * 128 + ((c * 2) ^ ((a & 7) << 4))) = pk;
  }
  __syncthreads();
  const int w = t >> 6, lane = t & 63;
  const int lr = lane & 15, lk = lane >> 4;
  const int sw = (lr & 7) << 4;
  const float AWS = SCALE * SCALE * LOG2E;
  // QK^T: 16 col-tiles, ONE per wave; awsh fp32 with causal mask baked in
  {
    int nt = w;
    floatx4 acc = (floatx4){0.f, 0.f, 0.f, 0.f};
    #pragma unroll
    for (int kc = 0; kc < 2; ++kc) {
      short8 af = *reinterpret_cast<const short8*>(
          qshc + lr * 128 + ((kc * 64 + lk * 16) ^ sw));
      int tt = nt * 16 + lr;
      short8 bf = *reinterpret_cast<const short8*>(
          kshc + tt * 128 + ((kc * 64 + lk * 16) ^ ((tt & 7) << 4)));
      acc = __builtin_amdgcn_mfma_f32_16x16x32_bf16(af, bf, acc, 0, 0, 0);
    }
    #pragma unroll
    for (int r = 0; r < 4; ++r) {
      int a = lk * 4 + r;
      int pr = a >> 3, mr = (a >> 2) & 1, jo = a & 3;
      int sa = mr ? 255 - (4 * u + jo) : 4 * u + jo;
      int tc = nt * 16 + lr;
      awsh[a][tc] = (tc <= sa) ? acc[r] * AWS : -1000.0f;
    }
  }
  __syncthreads();
  // wave w owns row a = w
  const int a = w;
  const int pr = a >> 3, mr = (a >> 2) & 1, jo = a & 3;
  const int h = 2 * g + pr;
  const int s = mr ? 255 - (4 * u + jo) : 4 * u + jo;
  size_t rowbase = ((size_t)h * 256 + s) * 256;
  // pre-loop: ep = 2^(8*aw); Sp shuffle-reduce; store NORMALIZED p (fp32)
  float epv[4], sp = 0.f;
  #pragma unroll
  for (int i = 0; i < 4; ++i) {
    epv[i] = __builtin_amdgcn_exp2f(8.0f * awsh[a][lane + i * 64]);
    sp += epv[i];
  }
  #pragma unroll
  for (int off = 32; off; off >>= 1) sp += __shfl_xor(sp, off);
  float invSp = 1.f / sp;
  float p2 = 0.f;
  #pragma unroll
  for (int i = 0; i < 4; ++i) {
    int tc = lane + i * 64;
    float pv = epv[i] * invSp;
    epsh[a][tc] = pv;
    pOut[rowbase + tc] = pv;                 // masked -> ep=0 -> p=0
    p2 = fmaf(pv, pv, p2);
  }
  #pragma unroll
  for (int off = 32; off; off >>= 1) p2 += __shfl_xor(p2, off);
  // slim t-loop: 4 chains (S1, S2, S3=sum e*p, AV=sum p*v)
  float cd2 = (SCALE * LOG2E) * QKV[(size_t)s * 2048 + h * 64 + lane];
  float S1 = 0.f, S2 = 0.f, S3 = 0.f, AV = 0.f;
  const uint32_t* kvrow = &kvT[lane * 258];
  const float* awrow = awsh[a];
  const float* prow = epsh[a];
  const int nt4 = (s + 4) & ~3;        // masked region contributes exact 0
  #pragma unroll 2
  for (int tb = 0; tb < nt4; tb += 4) {
    uint2 kvA = *reinterpret_cast<const uint2*>(&kvrow[tb]);
    uint2 kvB = *reinterpret_cast<const uint2*>(&kvrow[tb + 2]);
    float4 aw4 = *reinterpret_cast<const float4*>(&awrow[tb]);
    float4 p4 = *reinterpret_cast<const float4*>(&prow[tb]);
    uint32_t kvj[4] = {kvA.x, kvA.y, kvB.x, kvB.y};
    float awj[4] = {aw4.x, aw4.y, aw4.z, aw4.w};
    float pj[4] = {p4.x, p4.y, p4.z, p4.w};
    #pragma unroll
    for (int j = 0; j < 4; ++j) {
      float kf = __uint_as_float(kvj[j] << 16);
      float vf = __uint_as_float(kvj[j] & 0xFFFF0000u);
      float e = __builtin_amdgcn_exp2f(fmaf(-cd2, kf, awj[j]));
      S1 += e;
      S2 = fmaf(e, e, S2);
      S3 = fmaf(e, pj[j], S3);
      AV = fmaf(pj[j], vf, AV);
    }
  }
  float invS1 = 1.f / S1;
  float qk = S2 * invS1 * invS1 - 2.f * S3 * invS1 + p2;
  attn_out[(size_t)s * 1024 + h * 64 + lane] = AV;
  qkpart[((size_t)h * 256 + s) * 64 + lane] = qk;
}

// ---------------------------------------------------------------------------
// GEMM 2 + tail in ONE dispatch. Blocks 0..255: 32x32-tile FULL-K bf16 MFMA,
// direct write to out. Blocks 256..263: qk (sum 256 rows) / v/o importance
// (sum |attn_out|). grid = 264, block = 256.  (verified R22/R23)
// ---------------------------------------------------------------------------
__global__ __launch_bounds__(256) void gemm_o_tail_kernel(
    const float* __restrict__ A, const float* __restrict__ W,
    const float* __restrict__ qkpart, float* __restrict__ out,
    float* __restrict__ qkout, float* __restrict__ vout,
    float* __restrict__ oout) {
  __shared__ ushort As[2048];   // 32 rows x 64 k bf16, XOR swizzle
  __shared__ ushort Bs[2048];   // 32 n    x 64 k
  char* Asc = (char*)As;
  char* Bsc = (char*)Bs;
  const int b = blockIdx.x, t = threadIdx.x;
  if (b < 256) {
    const int tm = b >> 5, tn = b & 31;       // 8 m x 32 n tiles
    const int m0 = tm * 32, n0 = tn * 32;
    const int arow = t >> 3, aslot = t & 7;   // A: 32 rows x 16 slots
    const int kp = t >> 3, ng = t & 7;        // B: 32 kpairs x 8 ngroups
    float4 ra[2], rb0, rb1;
    auto LOAD = [&](int k0) {
      #pragma unroll
      for (int i = 0; i < 2; ++i)
        ra[i] = *reinterpret_cast<const float4*>(A + (size_t)(m0 + arow) * 1024 + k0 + (aslot + 8 * i) * 4);
      rb0 = *reinterpret_cast<const float4*>(W + (size_t)(k0 + 2 * kp) * 1024 + n0 + ng * 4);
      rb1 = *reinterpret_cast<const float4*>(W + (size_t)(k0 + 2 * kp + 1) * 1024 + n0 + ng * 4);
    };
    LOAD(0);
    const int wid = t >> 6, qm = wid >> 1, qn = wid & 1, lane = t & 63;
    const int lr = lane & 15, lk = lane >> 4;
    const int sw = (lr & 7) << 4;
    floatx4 acc = (floatx4){0.f, 0.f, 0.f, 0.f};
    for (int kt = 0; kt < 16; ++kt) {
      #pragma unroll
      for (int i = 0; i < 2; ++i) {
        int c = (aslot + 8 * i) * 4;
        ushort4 wv;
        wv.x = f2bf(ra[i].x); wv.y = f2bf(ra[i].y); wv.z = f2bf(ra[i].z); wv.w = f2bf(ra[i].w);
        *reinterpret_cast<ushort4*>(Asc + arow * 128 + ((c * 2) ^ ((arow & 7) << 4))) = wv;
      }
      {
        const float* p0 = (const float*)&rb0;
        const float* p1 = (const float*)&rb1;
        #pragma unroll
        for (int j = 0; j < 4; ++j) {
          int n = ng * 4 + j;
          uint32_t v = (uint32_t)f2bf(p0[j]) | ((uint32_t)f2bf(p1[j]) << 16);
          *reinterpret_cast<uint32_t*>(Bsc + n * 128 + ((kp * 4) ^ ((n & 7) << 4))) = v;
        }
      }
      __syncthreads();
      if (kt + 1 < 16) LOAD(64 * (kt + 1));
      #pragma unroll
      for (int kc = 0; kc < 2; ++kc) {
        short8 af = *reinterpret_cast<const short8*>(
            Asc + (qm * 16 + lr) * 128 + ((kc * 64 + lk * 16) ^ sw));
        short8 bf = *reinterpret_cast<const short8*>(
            Bsc + (qn * 16 + lr) * 128 + ((kc * 64 + lk * 16) ^ sw));
        acc = __builtin_amdgcn_mfma_f32_16x16x32_bf16(af, bf, acc, 0, 0, 0);
      }
      __syncthreads();
    }
    #pragma unroll
    for (int r = 0; r < 4; ++r) {
      int row = m0 + qm * 16 + lk * 4 + r;
      int col = n0 + qn * 16 + lr;
      out[(size_t)row * 1024 + col] = acc[r];
    }
  } else {
    int idx = (b - 256) * 256 + t;            // 0..2047
    if (idx < 1024) {
      int h = idx >> 6, d = idx & 63;
      float sum = 0.f;
      for (int j = 0; j < 256; ++j) sum += qkpart[((size_t)h * 256 + j) * 64 + d];
      qkout[idx] = sum;
    } else {
      int c = idx - 1024;
      float sum = 0.f;
      for (int s = 0; s < 256; ++s) sum += fabsf(A[(size_t)s * 1024 + c]);
      vout[c] = sum;
      oout[c] = sum;
    }
  }
}

// ---------------------------------------------------------------------------
extern "C" void kernel_launch(void* const* d_in, const int* in_sizes, int n_in,
                              void* d_out, int out_size, void* d_ws, size_t ws_size,
                              hipStream_t stream) {
  const float* X    = (const float*)d_in[0];   // hidden_states (1,256,1024)
  const float* cosp = (const float*)d_in[1];   // (1,256,64)
  const float* sinp = (const float*)d_in[2];   // (1,256,64)
  // d_in[3] attention_mask: causal, implemented analytically
  const float* Wq   = (const float*)d_in[4];   // (1024,1024)
  const float* Wk   = (const float*)d_in[5];   // (1024,512)
  const float* Wv   = (const float*)d_in[6];   // (1024,512)
  const float* Wo   = (const float*)d_in[7];   // (1024,1024)

  float* out  = (float*)d_out;                 // 262144
  float* pOut = out + 262144;                  // 1048576
  float* qki  = pOut + 1048576;                // 1024
  float* vi   = qki + 1024;                    // 1024
  float* oi   = vi + 1024;                     // 1024

  float* ws       = (float*)d_ws;
  float* QKV      = ws;                        // 524288 (s-major, 2048 cols: q|k|v)
  float* attn_out = ws + 524288;               // 262144
  float* qkpart   = ws + 786432;               // 262144 (per-row qk)
  float* scratch  = ws + 1048576;              // 2097152 (QKV partials x4)

  hipLaunchKernelGGL(gemm_qkv_kernel, dim3(512), dim3(256), 0, stream, X, Wq, Wk, Wv, scratch);
  hipLaunchKernelGGL(rope_reduce_kernel, dim3(1280), dim3(256), 0, stream, scratch, QKV, cosp, sinp);
  hipLaunchKernelGGL(pdiff_fused_kernel, dim3(256), dim3(1024), 0, stream, QKV, pOut, qkpart, attn_out);
  hipLaunchKernelGGL(gemm_o_tail_kernel, dim3(264), dim3(256), 0, stream, attn_out, Wo, qkpart, out, qki, vi, oi);
}

// Round 29
// 40.559 us; speedup vs baseline: 1.0326x; 1.0132x over previous
//
#include <hip/hip_runtime.h>
#include <math.h>

// Problem constants: B=1, S=256, HID=1024, H=16, KV=8, D=64, N_REP=2
#define SCALE 0.125f   // 1/sqrt(64)
#define LOG2E 1.44269504088896340736f

typedef short short8 __attribute__((ext_vector_type(8)));
typedef float floatx4 __attribute__((ext_vector_type(4)));

static __device__ __forceinline__ ushort f2bf(float x) {
  uint32_t b = __float_as_uint(x);
  uint32_t r = (b + 0x7FFFu + ((b >> 16) & 1u)) >> 16;   // RNE
  return (ushort)r;
}
static __device__ __forceinline__ float bf2f(ushort u) {
  return __uint_as_float(((uint32_t)u) << 16);
}

// ---------------------------------------------------------------------------
// MFMA bf16 GEMM 1: X(256x1024) @ [Wq|Wk|Wv](1024x2048) -> QKV partials.
// K-split 4. grid = 512 (4 ksplit * 128 tiles), block = 256. (verified R8/R13)
// ---------------------------------------------------------------------------
__global__ __launch_bounds__(256) void gemm_qkv_kernel(
    const float* __restrict__ X, const float* __restrict__ Wq,
    const float* __restrict__ Wk, const float* __restrict__ Wv,
    float* __restrict__ Cp) {
  __shared__ ushort As[4096];
  __shared__ ushort Bs[4096];
  char* Asc = (char*)As;
  char* Bsc = (char*)Bs;
  const int bx = blockIdx.x;
  const int ks = bx >> 7;            // 0..3
  const int tile = bx & 127;         // 4 m-tiles x 32 n-tiles
  const int tile_n = tile & 31, tile_m = tile >> 5;
  const int n0 = tile_n * 64, m0 = tile_m * 64;
  const float* Bp; int ldb, bc0;
  if (n0 < 1024)      { Bp = Wq; ldb = 1024; bc0 = n0; }
  else if (n0 < 1536) { Bp = Wk; ldb = 512;  bc0 = n0 - 1024; }
  else                { Bp = Wv; ldb = 512;  bc0 = n0 - 1536; }
  const int t = threadIdx.x;
  const int arow = t >> 4, acg = t & 15;
  const int bng = t & 15;
  const int kbeg = ks * 256;
  float4 ra[4], rb0[2], rb1[2];
  auto LOAD = [&](int k0) {
    #pragma unroll
    for (int i = 0; i < 4; ++i)
      ra[i] = *reinterpret_cast<const float4*>(X + (size_t)(m0 + arow + 16 * i) * 1024 + k0 + acg * 4);
    #pragma unroll
    for (int i = 0; i < 2; ++i) {
      int k = 2 * ((t >> 4) + 16 * i);
      rb0[i] = *reinterpret_cast<const float4*>(Bp + (size_t)(k0 + k) * ldb + bc0 + bng * 4);
      rb1[i] = *reinterpret_cast<const float4*>(Bp + (size_t)(k0 + k + 1) * ldb + bc0 + bng * 4);
    }
  };
  LOAD(kbeg);
  const int wid = t >> 6, wr = wid >> 1, wc = wid & 1, lane = t & 63;
  const int lr = lane & 15, lk = lane >> 4;
  const int sw = (lr & 7) << 4;
  floatx4 acc[2][2];
  #pragma unroll
  for (int mt = 0; mt < 2; ++mt)
    #pragma unroll
    for (int nt = 0; nt < 2; ++nt)
      acc[mt][nt] = (floatx4){0.f, 0.f, 0.f, 0.f};
  for (int kt = 0; kt < 4; ++kt) {
    #pragma unroll
    for (int i = 0; i < 4; ++i) {
      int row = arow + 16 * i;
      ushort4 w;
      w.x = f2bf(ra[i].x); w.y = f2bf(ra[i].y); w.z = f2bf(ra[i].z); w.w = f2bf(ra[i].w);
      *reinterpret_cast<ushort4*>(Asc + row * 128 + ((acg * 8) ^ ((row & 7) << 4))) = w;
    }
    #pragma unroll
    for (int i = 0; i < 2; ++i) {
      int k = 2 * ((t >> 4) + 16 * i);
      const float* p0 = (const float*)&rb0[i];
      const float* p1 = (const float*)&rb1[i];
      #pragma unroll
      for (int j = 0; j < 4; ++j) {
        int n = bng * 4 + j;
        uint32_t v = (uint32_t)f2bf(p0[j]) | ((uint32_t)f2bf(p1[j]) << 16);
        *reinterpret_cast<uint32_t*>(Bsc + n * 128 + ((k * 2) ^ ((n & 7) << 4))) = v;
      }
    }
    __syncthreads();
    if (kt + 1 < 4) LOAD(kbeg + 64 * (kt + 1));
    #pragma unroll
    for (int kc = 0; kc < 2; ++kc) {
      short8 af[2], bf[2];
      #pragma unroll
      for (int mt = 0; mt < 2; ++mt)
        af[mt] = *reinterpret_cast<const short8*>(
            Asc + (wr * 32 + mt * 16 + lr) * 128 + ((kc * 64 + lk * 16) ^ sw));
      #pragma unroll
      for (int nt = 0; nt < 2; ++nt)
        bf[nt] = *reinterpret_cast<const short8*>(
            Bsc + (wc * 32 + nt * 16 + lr) * 128 + ((kc * 64 + lk * 16) ^ sw));
      #pragma unroll
      for (int mt = 0; mt < 2; ++mt)
        #pragma unroll
        for (int nt = 0; nt < 2; ++nt)
          acc[mt][nt] = __builtin_amdgcn_mfma_f32_16x16x32_bf16(af[mt], bf[nt], acc[mt][nt], 0, 0, 0);
    }
    __syncthreads();
  }
  float* Co = Cp + (size_t)ks * 524288;
  #pragma unroll
  for (int mt = 0; mt < 2; ++mt)
    #pragma unroll
    for (int nt = 0; nt < 2; ++nt)
      #pragma unroll
      for (int r = 0; r < 4; ++r) {
        int row = wr * 32 + mt * 16 + lk * 4 + r;
        int col = wc * 32 + nt * 16 + lr;
        Co[(size_t)(m0 + row) * 2048 + n0 + col] = acc[mt][nt][r];
      }
}

// ---------------------------------------------------------------------------
// Reduce the 4 QKV partials + RoPE on q/k heads. grid = 1280, block = 256.
// ---------------------------------------------------------------------------
__global__ __launch_bounds__(256) void rope_reduce_kernel(
    const float* __restrict__ Cp, float* __restrict__ QKV,
    const float* __restrict__ cs, const float* __restrict__ sn) {
  int idx = blockIdx.x * 256 + threadIdx.x;
  const float* P0 = Cp;
  const float* P1 = Cp + 524288;
  const float* P2p = Cp + 1048576;
  const float* P3 = Cp + 1572864;
  if (idx < 196608) {                 // 256 s * 24 heads * 32 pairs
    int dp = idx & 31;
    int head = (idx >> 5) % 24;       // 0..15 q heads, 16..23 k heads
    int s = idx / 768;
    int base = s * 2048 + head * 64;
    int a1 = base + dp, a2 = base + dp + 32;
    float x1 = P0[a1] + P1[a1] + P2p[a1] + P3[a1];
    float x2 = P0[a2] + P1[a2] + P2p[a2] + P3[a2];
    float c1 = cs[s * 64 + dp],      s1v = sn[s * 64 + dp];
    float c2 = cs[s * 64 + dp + 32], s2v = sn[s * 64 + dp + 32];
    QKV[a1] = x1 * c1 - x2 * s1v;   // q' = q*cos + rot_half(q)*sin
    QKV[a2] = x2 * c2 + x1 * s2v;
  } else {
    int i2 = idx - 196608;            // 131072 v elements
    int s = i2 >> 9, c = 1536 + (i2 & 511);
    int a = s * 2048 + c;
    QKV[a] = P0[a] + P1[a] + P2p[a] + P3[a];
  }
}

// ---------------------------------------------------------------------------
// FUSED QK^T + softmax + p_diff + PV, v11 = R24 + REGISTER SOFTWARE PIPELINE.
// Arithmetic: pdiff ~25us = ~29 cyc/iter/wave vs ~9 issue slots -> LDS load
// LATENCY with insufficient lookahead (loads issued just before use; all 4
// waves/SIMD stall in near-lockstep). Fix: unconditionally prefetch group
// tb+4 into regs before computing group tb (kvT padded +8 words so the last
// prefetch stays in-bounds). No barriers in this loop (unlike m133's null).
// LDS 131KB, grid 256, block 1024.
// ---------------------------------------------------------------------------
__global__ __launch_bounds__(1024) void pdiff_fused_kernel(
    const float* __restrict__ QKV, float* __restrict__ pOut,
    float* __restrict__ qkpart, float* __restrict__ attn_out) {
  __shared__ ushort ksh[16384];          // 32KB swizzled [t][d] bf16 (MFMA B)
  __shared__ uint32_t kvT[64 * 258 + 8]; // 64.5KB+pad [d][t]: k lo | v hi
  __shared__ ushort qsh[1024];           // 2KB swizzled [a][d] bf16 (16 rows)
  __shared__ float awsh[16][260];        // 16.25KB fp32 (masked aw)
  __shared__ float epsh[16][260];        // 16.25KB fp32 normalized p per row
  char* kshc = (char*)ksh;
  char* qshc = (char*)qsh;
  const int g = blockIdx.x >> 5;
  const int u = blockIdx.x & 31;
  const int t = threadIdx.x;
  // stage k (swizzled, for MFMA) + kvT (transposed packed, for t-loop)
  #pragma unroll
  for (int i = 0; i < 4; ++i) {
    int fi = t + i * 1024;             // 4096 float4 slots
    int tt = fi >> 4, c = (fi & 15) * 4;
    float4 kv = *reinterpret_cast<const float4*>(QKV + (size_t)tt * 2048 + 1024 + g * 64 + c);
    float4 vv = *reinterpret_cast<const float4*>(QKV + (size_t)tt * 2048 + 1536 + g * 64 + c);
    ushort4 wk;
    wk.x = f2bf(kv.x); wk.y = f2bf(kv.y); wk.z = f2bf(kv.z); wk.w = f2bf(kv.w);
    *reinterpret_cast<ushort4*>(kshc + tt * 128 + ((c * 2) ^ ((tt & 7) << 4))) = wk;
    kvT[(c + 0) * 258 + tt] = (uint32_t)wk.x | ((uint32_t)f2bf(vv.x) << 16);
    kvT[(c + 1) * 258 + tt] = (uint32_t)wk.y | ((uint32_t)f2bf(vv.y) << 16);
    kvT[(c + 2) * 258 + tt] = (uint32_t)wk.z | ((uint32_t)f2bf(vv.z) << 16);
    kvT[(c + 3) * 258 + tt] = (uint32_t)wk.w | ((uint32_t)f2bf(vv.w) << 16);
  }
  if (t < 512) { // stage the 16 q rows: a = pr*8 + mr*4 + jo
    int a = t >> 5;                    // 0..15
    int c = (t & 31) * 2;              // 0..62
    int pr = a >> 3, mr = (a >> 2) & 1, jo = a & 3;
    int s = mr ? 255 - (4 * u + jo) : 4 * u + jo;
    int hh = 2 * g + pr;
    float2 qv = *reinterpret_cast<const float2*>(QKV + (size_t)s * 2048 + hh * 64 + c);
    uint32_t pk = (uint32_t)f2bf(qv.x) | ((uint32_t)f2bf(qv.y) << 16);
    *reinterpret_cast<uint32_t*>(qshc + a * 128 + ((c * 2) ^ ((a & 7) << 4))) = pk;
  }
  __syncthreads();
  const int w = t >> 6, lane = t & 63;
  const int lr = lane & 15, lk = lane >> 4;
  const int sw = (lr & 7) << 4;
  const float AWS = SCALE * SCALE * LOG2E;
  // QK^T: 16 col-tiles, ONE per wave; awsh fp32 with causal mask baked in
  {
    int nt = w;
    floatx4 acc = (floatx4){0.f, 0.f, 0.f, 0.f};
    #pragma unroll
    for (int kc = 0; kc < 2; ++kc) {
      short8 af = *reinterpret_cast<const short8*>(
          qshc + lr * 128 + ((kc * 64 + lk * 16) ^ sw));
      int tt = nt * 16 + lr;
      short8 bf = *reinterpret_cast<const short8*>(
          kshc + tt * 128 + ((kc * 64 + lk * 16) ^ ((tt & 7) << 4)));
      acc = __builtin_amdgcn_mfma_f32_16x16x32_bf16(af, bf, acc, 0, 0, 0);
    }
    #pragma unroll
    for (int r = 0; r < 4; ++r) {
      int a = lk * 4 + r;
      int pr = a >> 3, mr = (a >> 2) & 1, jo = a & 3;
      int sa = mr ? 255 - (4 * u + jo) : 4 * u + jo;
      int tc = nt * 16 + lr;
      awsh[a][tc] = (tc <= sa) ? acc[r] * AWS : -1000.0f;
    }
  }
  __syncthreads();
  // wave w owns row a = w
  const int a = w;
  const int pr = a >> 3, mr = (a >> 2) & 1, jo = a & 3;
  const int h = 2 * g + pr;
  const int s = mr ? 255 - (4 * u + jo) : 4 * u + jo;
  size_t rowbase = ((size_t)h * 256 + s) * 256;
  // pre-loop: ep = 2^(8*aw); Sp shuffle-reduce; store NORMALIZED p (fp32)
  float epv[4], sp = 0.f;
  #pragma unroll
  for (int i = 0; i < 4; ++i) {
    epv[i] = __builtin_amdgcn_exp2f(8.0f * awsh[a][lane + i * 64]);
    sp += epv[i];
  }
  #pragma unroll
  for (int off = 32; off; off >>= 1) sp += __shfl_xor(sp, off);
  float invSp = 1.f / sp;
  float p2 = 0.f;
  #pragma unroll
  for (int i = 0; i < 4; ++i) {
    int tc = lane + i * 64;
    float pv = epv[i] * invSp;
    epsh[a][tc] = pv;
    pOut[rowbase + tc] = pv;                 // masked -> ep=0 -> p=0
    p2 = fmaf(pv, pv, p2);
  }
  #pragma unroll
  for (int off = 32; off; off >>= 1) p2 += __shfl_xor(p2, off);
  // t-loop with 1-group-ahead register prefetch (software pipeline)
  float cd2 = (SCALE * LOG2E) * QKV[(size_t)s * 2048 + h * 64 + lane];
  float S1 = 0.f, S2 = 0.f, S3 = 0.f, AV = 0.f;
  const uint32_t* kvrow = &kvT[lane * 258];
  const float* awrow = awsh[a];
  const float* prow = epsh[a];
  const int nt4 = (s + 4) & ~3;        // masked region contributes exact 0
  uint2 kvA = *reinterpret_cast<const uint2*>(&kvrow[0]);
  uint2 kvB = *reinterpret_cast<const uint2*>(&kvrow[2]);
  float4 aw4 = *reinterpret_cast<const float4*>(&awrow[0]);
  float4 p4 = *reinterpret_cast<const float4*>(&prow[0]);
  for (int tb = 0; tb < nt4; tb += 4) {
    // prefetch next group (unconditional; pads make tb+4..tb+7 in-bounds)
    int tbn = tb + 4;
    uint2 kvA2 = *reinterpret_cast<const uint2*>(&kvrow[tbn]);
    uint2 kvB2 = *reinterpret_cast<const uint2*>(&kvrow[tbn + 2]);
    float4 aw42 = *reinterpret_cast<const float4*>(&awrow[tbn < 256 ? tbn : 0]);
    float4 p42 = *reinterpret_cast<const float4*>(&prow[tbn < 256 ? tbn : 0]);
    uint32_t kvj[4] = {kvA.x, kvA.y, kvB.x, kvB.y};
    float awj[4] = {aw4.x, aw4.y, aw4.z, aw4.w};
    float pj[4] = {p4.x, p4.y, p4.z, p4.w};
    #pragma unroll
    for (int j = 0; j < 4; ++j) {
      float kf = __uint_as_float(kvj[j] << 16);
      float vf = __uint_as_float(kvj[j] & 0xFFFF0000u);
      float e = __builtin_amdgcn_exp2f(fmaf(-cd2, kf, awj[j]));
      S1 += e;
      S2 = fmaf(e, e, S2);
      S3 = fmaf(e, pj[j], S3);
      AV = fmaf(pj[j], vf, AV);
    }
    kvA = kvA2; kvB = kvB2; aw4 = aw42; p4 = p42;
  }
  float invS1 = 1.f / S1;
  float qk = S2 * invS1 * invS1 - 2.f * S3 * invS1 + p2;
  attn_out[(size_t)s * 1024 + h * 64 + lane] = AV;
  qkpart[((size_t)h * 256 + s) * 64 + lane] = qk;
}

// ---------------------------------------------------------------------------
// GEMM 2 + tail in ONE dispatch. Blocks 0..255: 32x32-tile FULL-K bf16 MFMA,
// direct write to out. Blocks 256..263: qk (sum 256 rows) / v/o importance
// (sum |attn_out|). grid = 264, block = 256.  (verified R22/R23)
// ---------------------------------------------------------------------------
__global__ __launch_bounds__(256) void gemm_o_tail_kernel(
    const float* __restrict__ A, const float* __restrict__ W,
    const float* __restrict__ qkpart, float* __restrict__ out,
    float* __restrict__ qkout, float* __restrict__ vout,
    float* __restrict__ oout) {
  __shared__ ushort As[2048];   // 32 rows x 64 k bf16, XOR swizzle
  __shared__ ushort Bs[2048];   // 32 n    x 64 k
  char* Asc = (char*)As;
  char* Bsc = (char*)Bs;
  const int b = blockIdx.x, t = threadIdx.x;
  if (b < 256) {
    const int tm = b >> 5, tn = b & 31;       // 8 m x 32 n tiles
    const int m0 = tm * 32, n0 = tn * 32;
    const int arow = t >> 3, aslot = t & 7;   // A: 32 rows x 16 slots
    const int kp = t >> 3, ng = t & 7;        // B: 32 kpairs x 8 ngroups
    float4 ra[2], rb0, rb1;
    auto LOAD = [&](int k0) {
      #pragma unroll
      for (int i = 0; i < 2; ++i)
        ra[i] = *reinterpret_cast<const float4*>(A + (size_t)(m0 + arow) * 1024 + k0 + (aslot + 8 * i) * 4);
      rb0 = *reinterpret_cast<const float4*>(W + (size_t)(k0 + 2 * kp) * 1024 + n0 + ng * 4);
      rb1 = *reinterpret_cast<const float4*>(W + (size_t)(k0 + 2 * kp + 1) * 1024 + n0 + ng * 4);
    };
    LOAD(0);
    const int wid = t >> 6, qm = wid >> 1, qn = wid & 1, lane = t & 63;
    const int lr = lane & 15, lk = lane >> 4;
    const int sw = (lr & 7) << 4;
    floatx4 acc = (floatx4){0.f, 0.f, 0.f, 0.f};
    for (int kt = 0; kt < 16; ++kt) {
      #pragma unroll
      for (int i = 0; i < 2; ++i) {
        int c = (aslot + 8 * i) * 4;
        ushort4 wv;
        wv.x = f2bf(ra[i].x); wv.y = f2bf(ra[i].y); wv.z = f2bf(ra[i].z); wv.w = f2bf(ra[i].w);
        *reinterpret_cast<ushort4*>(Asc + arow * 128 + ((c * 2) ^ ((arow & 7) << 4))) = wv;
      }
      {
        const float* p0 = (const float*)&rb0;
        const float* p1 = (const float*)&rb1;
        #pragma unroll
        for (int j = 0; j < 4; ++j) {
          int n = ng * 4 + j;
          uint32_t v = (uint32_t)f2bf(p0[j]) | ((uint32_t)f2bf(p1[j]) << 16);
          *reinterpret_cast<uint32_t*>(Bsc + n * 128 + ((kp * 4) ^ ((n & 7) << 4))) = v;
        }
      }
      __syncthreads();
      if (kt + 1 < 16) LOAD(64 * (kt + 1));
      #pragma unroll
      for (int kc = 0; kc < 2; ++kc) {
        short8 af = *reinterpret_cast<const short8*>(
            Asc + (qm * 16 + lr) * 128 + ((kc * 64 + lk * 16) ^ sw));
        short8 bf = *reinterpret_cast<const short8*>(
            Bsc + (qn * 16 + lr) * 128 + ((kc * 64 + lk * 16) ^ sw));
        acc = __builtin_amdgcn_mfma_f32_16x16x32_bf16(af, bf, acc, 0, 0, 0);
      }
      __syncthreads();
    }
    #pragma unroll
    for (int r = 0; r < 4; ++r) {
      int row = m0 + qm * 16 + lk * 4 + r;
      int col = n0 + qn * 16 + lr;
      out[(size_t)row * 1024 + col] = acc[r];
    }
  } else {
    int idx = (b - 256) * 256 + t;            // 0..2047
    if (idx < 1024) {
      int h = idx >> 6, d = idx & 63;
      float sum = 0.f;
      for (int j = 0; j < 256; ++j) sum += qkpart[((size_t)h * 256 + j) * 64 + d];
      qkout[idx] = sum;
    } else {
      int c = idx - 1024;
      float sum = 0.f;
      for (int s = 0; s < 256; ++s) sum += fabsf(A[(size_t)s * 1024 + c]);
      vout[c] = sum;
      oout[c] = sum;
    }
  }
}

// ---------------------------------------------------------------------------
extern "C" void kernel_launch(void* const* d_in, const int* in_sizes, int n_in,
                              void* d_out, int out_size, void* d_ws, size_t ws_size,
                              hipStream_t stream) {
  const float* X    = (const float*)d_in[0];   // hidden_states (1,256,1024)
  const float* cosp = (const float*)d_in[1];   // (1,256,64)
  const float* sinp = (const float*)d_in[2];   // (1,256,64)
  // d_in[3] attention_mask: causal, implemented analytically
  const float* Wq   = (const float*)d_in[4];   // (1024,1024)
  const float* Wk   = (const float*)d_in[5];   // (1024,512)
  const float* Wv   = (const float*)d_in[6];   // (1024,512)
  const float* Wo   = (const float*)d_in[7];   // (1024,1024)

  float* out  = (float*)d_out;                 // 262144
  float* pOut = out + 262144;                  // 1048576
  float* qki  = pOut + 1048576;                // 1024
  float* vi   = qki + 1024;                    // 1024
  float* oi   = vi + 1024;                     // 1024

  float* ws       = (float*)d_ws;
  float* QKV      = ws;                        // 524288 (s-major, 2048 cols: q|k|v)
  float* attn_out = ws + 524288;               // 262144
  float* qkpart   = ws + 786432;               // 262144 (per-row qk)
  float* scratch  = ws + 1048576;              // 2097152 (QKV partials x4)

  hipLaunchKernelGGL(gemm_qkv_kernel, dim3(512), dim3(256), 0, stream, X, Wq, Wk, Wv, scratch);
  hipLaunchKernelGGL(rope_reduce_kernel, dim3(1280), dim3(256), 0, stream, scratch, QKV, cosp, sinp);
  hipLaunchKernelGGL(pdiff_fused_kernel, dim3(256), dim3(1024), 0, stream, QKV, pOut, qkpart, attn_out);
  hipLaunchKernelGGL(gemm_o_tail_kernel, dim3(264), dim3(256), 0, stream, attn_out, Wo, qkpart, out, qki, vi, oi);
}